// Round 5
// baseline (391.912 us; speedup 1.0000x reference)
//
#include <hip/hip_runtime.h>
#include <hip/hip_bf16.h>
#include <stdint.h>

#define S_LEN 2048
#define E_DIM 1024
#define NHEAD 16
#define DHEAD 64
#define NB 2
#define NROWS (NB * S_LEN)   // 4096

typedef __attribute__((ext_vector_type(8))) short bf16x8;
typedef __attribute__((ext_vector_type(4))) float f32x4;

__device__ __forceinline__ unsigned short f2b(float f) {
    union { __hip_bfloat16 h; unsigned short u; } cv;
    cv.h = __float2bfloat16(f);
    return cv.u;
}

// async global->LDS, 16B per lane. LDS dest is wave-uniform base + lane*16.
__device__ __forceinline__ void gload_lds16(const void* g, void* l) {
    __builtin_amdgcn_global_load_lds(
        (const __attribute__((address_space(1))) unsigned int*)g,
        (__attribute__((address_space(3))) unsigned int*)l, 16, 0, 0);
}

// ------------------------------------------------ weight fp32[k][n] -> bf16 WT[n][k]
__global__ __launch_bounds__(256) void wtrans_kernel(
    const float* __restrict__ wq, const float* __restrict__ wk,
    const float* __restrict__ wv, const float* __restrict__ w0,
    unsigned short* __restrict__ wqT, unsigned short* __restrict__ wkT,
    unsigned short* __restrict__ wvT, unsigned short* __restrict__ w0T) {
    const int z = blockIdx.z;
    const float* W = (z == 0) ? wq : (z == 1) ? wk : (z == 2) ? wv : w0;
    unsigned short* WT = (z == 0) ? wqT : (z == 1) ? wkT : (z == 2) ? wvT : w0T;
    const int k0 = blockIdx.x * 64;
    const int n0 = blockIdx.y * 64;
    __shared__ float tile[64][69];   // 69: bank-spread for column reads
    const int t = threadIdx.x;
    const int rowq = t >> 4;          // 0..15
    const int cc4 = (t & 15) * 4;
    #pragma unroll
    for (int rr = 0; rr < 4; ++rr) {
        const int r = rr * 16 + rowq;
        const float4 v = *reinterpret_cast<const float4*>(W + (size_t)(k0 + r) * E_DIM + n0 + cc4);
        tile[r][cc4 + 0] = v.x; tile[r][cc4 + 1] = v.y;
        tile[r][cc4 + 2] = v.z; tile[r][cc4 + 3] = v.w;
    }
    __syncthreads();
    #pragma unroll
    for (int rr = 0; rr < 4; ++rr) {
        const int n = rr * 16 + rowq;
        ushort4 o;
        o.x = f2b(tile[cc4 + 0][n]);
        o.y = f2b(tile[cc4 + 1][n]);
        o.z = f2b(tile[cc4 + 2][n]);
        o.w = f2b(tile[cc4 + 3][n]);
        *reinterpret_cast<ushort4*>(WT + (size_t)(n0 + n) * E_DIM + k0 + cc4) = o;
    }
}

// ------------------------------------------------ LayerNorm -> bf16
__global__ __launch_bounds__(256) void ln_kernel(const float* __restrict__ x,
    const float* __restrict__ g, const float* __restrict__ bt,
    unsigned short* __restrict__ xn) {
    const int row = blockIdx.x;
    const int t = threadIdx.x;
    const float4 v = reinterpret_cast<const float4*>(x + (size_t)row * E_DIM)[t];
    float s  = v.x + v.y + v.z + v.w;
    float ss = v.x * v.x + v.y * v.y + v.z * v.z + v.w * v.w;
    #pragma unroll
    for (int off = 32; off > 0; off >>= 1) {
        s  += __shfl_down(s, off);
        ss += __shfl_down(ss, off);
    }
    __shared__ float red[8];
    if ((t & 63) == 0) { red[t >> 6] = s; red[(t >> 6) + 4] = ss; }
    __syncthreads();
    s  = red[0] + red[1] + red[2] + red[3];
    ss = red[4] + red[5] + red[6] + red[7];
    const float mu  = s * (1.0f / E_DIM);
    const float var = ss * (1.0f / E_DIM) - mu * mu;
    const float rs  = rsqrtf(var + 1e-5f);
    const float4 gv = reinterpret_cast<const float4*>(g)[t];
    const float4 bv = reinterpret_cast<const float4*>(bt)[t];
    ushort4 o;
    o.x = f2b((v.x - mu) * rs * gv.x + bv.x);
    o.y = f2b((v.y - mu) * rs * gv.y + bv.y);
    o.z = f2b((v.z - mu) * rs * gv.z + bv.z);
    o.w = f2b((v.w - mu) * rs * gv.w + bv.w);
    reinterpret_cast<ushort4*>(xn + (size_t)row * E_DIM)[t] = o;
}

// ------------------------------------------------ shared 128x128xK mainloop
// A [M][1024] bf16 row-major, BT [N][1024] bf16 row-major (= B^T).
// LDS tiles [128][64] with 16B-slot XOR swizzle: LDS(row, s) = global(row, s ^ (row&7)).
__device__ __forceinline__ void gemm128_mainloop(
    const unsigned short* __restrict__ A, const unsigned short* __restrict__ BT,
    int m0, int n0, unsigned short* As, unsigned short* Bs, f32x4 acc[4][4]) {
    const int t = threadIdx.x;
    const int l = t & 63;
    const int w = t >> 6;
    const int wr = w >> 1, wc = w & 1;
    const int lr = l >> 3;          // row within 8-row staging chunk
    const int gs = (l & 7) ^ lr;    // pre-swizzled source slot
    const int il = l & 15;          // fragment row
    const int kq = l >> 4;          // k quarter

    for (int kt = 0; kt < E_DIM; kt += 64) {
        __syncthreads();            // previous tile's reads done
        #pragma unroll
        for (int c = 0; c < 4; ++c) {
            const int cc = w * 4 + c;
            gload_lds16(A + (size_t)(m0 + cc * 8 + lr) * E_DIM + kt + gs * 8, As + cc * 512);
        }
        #pragma unroll
        for (int c = 0; c < 4; ++c) {
            const int cc = w * 4 + c;
            gload_lds16(BT + (size_t)(n0 + cc * 8 + lr) * E_DIM + kt + gs * 8, Bs + cc * 512);
        }
        __syncthreads();            // drains vmcnt -> tile ready
        #pragma unroll
        for (int ks = 0; ks < 2; ++ks) {
            bf16x8 af[4], bfr[4];
            #pragma unroll
            for (int mi = 0; mi < 4; ++mi) {
                const int r = wr * 64 + mi * 16 + il;
                af[mi] = *reinterpret_cast<const bf16x8*>(As + r * 64 + ((ks * 4 + kq) ^ (r & 7)) * 8);
            }
            #pragma unroll
            for (int ni = 0; ni < 4; ++ni) {
                const int r = wc * 64 + ni * 16 + il;
                bfr[ni] = *reinterpret_cast<const bf16x8*>(Bs + r * 64 + ((ks * 4 + kq) ^ (r & 7)) * 8);
            }
            #pragma unroll
            for (int mi = 0; mi < 4; ++mi)
                #pragma unroll
                for (int ni = 0; ni < 4; ++ni)
                    acc[mi][ni] = __builtin_amdgcn_mfma_f32_16x16x32_bf16(af[mi], bfr[ni], acc[mi][ni], 0, 0, 0);
        }
    }
}

// ------------------------------------------------ QKV projection
// q: [b,h,s,d] bf16 pre-scaled by 1/8; k: [b,h,s,d] bf16; v: TRANSPOSED [b,h,d,s] bf16.
__global__ __launch_bounds__(256) void qkv_kernel(
    const unsigned short* __restrict__ xn,
    const unsigned short* __restrict__ wqT, const float* __restrict__ bq,
    const unsigned short* __restrict__ wkT, const float* __restrict__ bk,
    const unsigned short* __restrict__ wvT, const float* __restrict__ bv,
    unsigned short* __restrict__ qo, unsigned short* __restrict__ ko,
    unsigned short* __restrict__ vo) {
    __shared__ __align__(16) unsigned short As[8192];
    __shared__ __align__(16) unsigned short Bs[8192];
    const int mat = blockIdx.z;
    const unsigned short* BT = (mat == 0) ? wqT : (mat == 1) ? wkT : wvT;
    const float* bias = (mat == 0) ? bq : (mat == 1) ? bk : bv;
    const int m0 = blockIdx.x * 128, n0 = blockIdx.y * 128;

    const f32x4 ZERO = {0.f, 0.f, 0.f, 0.f};
    f32x4 acc[4][4];
    #pragma unroll
    for (int i = 0; i < 4; ++i)
        #pragma unroll
        for (int j = 0; j < 4; ++j) acc[i][j] = ZERO;

    gemm128_mainloop(xn, BT, m0, n0, As, Bs, acc);

    const int t = threadIdx.x, l = t & 63, w = t >> 6;
    const int wr = w >> 1, wc = w & 1;
    const int il = l & 15, kq = l >> 4;
    const int b = m0 >> 11;
    const float qsc = (mat == 0) ? 0.125f : 1.0f;
    unsigned short* outp = (mat == 0) ? qo : ko;

    #pragma unroll
    for (int ni = 0; ni < 4; ++ni) {
        const int n = n0 + wc * 64 + ni * 16 + il;
        const int h = n >> 6, d = n & 63;
        const float bb = bias[n];
        #pragma unroll
        for (int mi = 0; mi < 4; ++mi) {
            const int mbase = m0 + wr * 64 + mi * 16 + kq * 4;
            const int sbase = mbase & (S_LEN - 1);
            if (mat == 2) {
                ushort4 o;
                o.x = f2b(acc[mi][ni][0] + bb);
                o.y = f2b(acc[mi][ni][1] + bb);
                o.z = f2b(acc[mi][ni][2] + bb);
                o.w = f2b(acc[mi][ni][3] + bb);
                *reinterpret_cast<ushort4*>(vo + ((size_t)(b * NHEAD + h) * DHEAD + d) * S_LEN + sbase) = o;
            } else {
                #pragma unroll
                for (int r = 0; r < 4; ++r)
                    outp[((size_t)(b * NHEAD + h) * S_LEN + sbase + r) * DHEAD + d] =
                        f2b((acc[mi][ni][r] + bb) * qsc);
            }
        }
    }
}

// ------------------------------------------------ flash attention (mask: attend j >= i)
// K/V are L2-resident per (b,h) (256 KB each): read MFMA fragments DIRECTLY from
// global (each lane's 16B chunk IS its fragment slice) — no K/V LDS staging, no
// __syncthreads in the loop. Only the per-wave P tile round-trips through LDS.
__global__ __launch_bounds__(256) void attn_kernel(
    const unsigned short* __restrict__ q,    // [bh][s][d], pre-scaled
    const unsigned short* __restrict__ k,    // [bh][s][d]
    const unsigned short* __restrict__ vt,   // [bh][d][s]
    unsigned short* __restrict__ hb) {       // [4096][1024] bf16
    __shared__ __align__(16) unsigned short Ps[4096];
    const int qi0 = blockIdx.x * 64;
    const int bh = blockIdx.y;
    const unsigned short* qp = q + (size_t)bh * S_LEN * DHEAD;
    const unsigned short* kp = k + (size_t)bh * S_LEN * DHEAD;
    const unsigned short* vp = vt + (size_t)bh * DHEAD * S_LEN;
    const int t = threadIdx.x, l = t & 63, w = t >> 6;
    const int il = l & 15, kq = l >> 4;

    const f32x4 ZERO = {0.f, 0.f, 0.f, 0.f};
    bf16x8 qf[2];
    const int qrow = qi0 + w * 16 + il;
    qf[0] = *reinterpret_cast<const bf16x8*>(qp + (size_t)qrow * DHEAD + kq * 8);
    qf[1] = *reinterpret_cast<const bf16x8*>(qp + (size_t)qrow * DHEAD + 32 + kq * 8);

    float m[4], lsum[4];
    f32x4 o[4];
    #pragma unroll
    for (int r = 0; r < 4; ++r) { m[r] = -INFINITY; lsum[r] = 0.f; }
    #pragma unroll
    for (int nf = 0; nf < 4; ++nf) o[nf] = ZERO;

    unsigned short* Pw = Ps + w * 1024;   // per-wave 16x64 P tile

    for (int kt0 = qi0; kt0 < S_LEN; kt0 += 64) {
        // ---- QK^T: K fragments straight from global/L2.
        // Lane (il,kq), frag nf, slice ks reads K[kt0+nf*16+il][ (ks*4+kq)*8 .. +8 ].
        bf16x8 kf[2][4];
        #pragma unroll
        for (int ks = 0; ks < 2; ++ks)
            #pragma unroll
            for (int nf = 0; nf < 4; ++nf)
                kf[ks][nf] = *reinterpret_cast<const bf16x8*>(
                    kp + (size_t)(kt0 + nf * 16 + il) * DHEAD + (ks * 4 + kq) * 8);
        f32x4 s[4];
        #pragma unroll
        for (int nf = 0; nf < 4; ++nf) s[nf] = ZERO;
        #pragma unroll
        for (int ks = 0; ks < 2; ++ks)
            #pragma unroll
            for (int nf = 0; nf < 4; ++nf)
                s[nf] = __builtin_amdgcn_mfma_f32_16x16x32_bf16(qf[ks], kf[ks][nf], s[nf], 0, 0, 0);

        if (kt0 == qi0) {   // diagonal tile: mask j < i
            #pragma unroll
            for (int nf = 0; nf < 4; ++nf) {
                const int j = kt0 + nf * 16 + il;
                #pragma unroll
                for (int r = 0; r < 4; ++r) {
                    const int i = qi0 + w * 16 + kq * 4 + r;
                    if (j < i) s[nf][r] = -INFINITY;
                }
            }
        }

        // ---- online softmax (16-lane row groups: il varies, kq fixed)
        float tm[4];
        #pragma unroll
        for (int r = 0; r < 4; ++r)
            tm[r] = fmaxf(fmaxf(s[0][r], s[1][r]), fmaxf(s[2][r], s[3][r]));
        #pragma unroll
        for (int msk = 8; msk; msk >>= 1)
            #pragma unroll
            for (int r = 0; r < 4; ++r)
                tm[r] = fmaxf(tm[r], __shfl_xor(tm[r], msk));

        float sc_[4];
        #pragma unroll
        for (int r = 0; r < 4; ++r) {
            const float nm = fmaxf(m[r], tm[r]);
            sc_[r] = __expf(m[r] - nm);
            m[r] = nm;
        }

        float ps[4] = {0.f, 0.f, 0.f, 0.f};
        #pragma unroll
        for (int nf = 0; nf < 4; ++nf)
            #pragma unroll
            for (int r = 0; r < 4; ++r) {
                const float pv = __expf(s[nf][r] - m[r]);
                ps[r] += pv;
                const int i = kq * 4 + r;
                const int col = nf * 16 + il;
                Pw[i * 64 + (((col >> 3) ^ (i & 7)) * 8) + (col & 7)] = f2b(pv);
            }
        #pragma unroll
        for (int msk = 8; msk; msk >>= 1)
            #pragma unroll
            for (int r = 0; r < 4; ++r)
                ps[r] += __shfl_xor(ps[r], msk);
        #pragma unroll
        for (int r = 0; r < 4; ++r) lsum[r] = lsum[r] * sc_[r] + ps[r];
        #pragma unroll
        for (int nf = 0; nf < 4; ++nf)
            #pragma unroll
            for (int r = 0; r < 4; ++r) o[nf][r] *= sc_[r];

        // ---- PV: V^T fragments straight from global/L2.
        // Lane (il,kq), frag nf, slice ks reads V^T[nf*16+il][ kt0+(ks*4+kq)*8 .. +8 ].
        bf16x8 vf[2][4];
        #pragma unroll
        for (int ks = 0; ks < 2; ++ks)
            #pragma unroll
            for (int nf = 0; nf < 4; ++nf)
                vf[ks][nf] = *reinterpret_cast<const bf16x8*>(
                    vp + (size_t)(nf * 16 + il) * S_LEN + kt0 + (ks * 4 + kq) * 8);
        asm volatile("s_waitcnt lgkmcnt(0)" ::: "memory");   // own-wave P writes visible
        #pragma unroll
        for (int ks = 0; ks < 2; ++ks) {
            const bf16x8 pa = *reinterpret_cast<const bf16x8*>(Pw + il * 64 + ((ks * 4 + kq) ^ (il & 7)) * 8);
            #pragma unroll
            for (int nf = 0; nf < 4; ++nf)
                o[nf] = __builtin_amdgcn_mfma_f32_16x16x32_bf16(pa, vf[ks][nf], o[nf], 0, 0, 0);
        }
    }

    const int b = bh >> 4, hh = bh & 15;
    float rl[4];
    #pragma unroll
    for (int r = 0; r < 4; ++r) rl[r] = 1.0f / lsum[r];
    #pragma unroll
    for (int nf = 0; nf < 4; ++nf) {
        const int col = hh * 64 + nf * 16 + il;
        #pragma unroll
        for (int r = 0; r < 4; ++r) {
            const int srow = qi0 + w * 16 + kq * 4 + r;
            hb[(size_t)(b * S_LEN + srow) * E_DIM + col] = f2b(o[nf][r] * rl[r]);
        }
    }
}

// ------------------------------------------------ output proj + bias + residual
__global__ __launch_bounds__(256) void oproj_kernel(
    const unsigned short* __restrict__ hbuf, const unsigned short* __restrict__ w0T,
    const float* __restrict__ b0, const float* __restrict__ x,
    float* __restrict__ out) {
    __shared__ __align__(16) unsigned short As[8192];
    __shared__ __align__(16) unsigned short Bs[8192];
    const int m0 = blockIdx.x * 128, n0 = blockIdx.y * 128;

    const f32x4 ZERO = {0.f, 0.f, 0.f, 0.f};
    f32x4 acc[4][4];
    #pragma unroll
    for (int i = 0; i < 4; ++i)
        #pragma unroll
        for (int j = 0; j < 4; ++j) acc[i][j] = ZERO;

    gemm128_mainloop(hbuf, w0T, m0, n0, As, Bs, acc);

    const int t = threadIdx.x, l = t & 63, w = t >> 6;
    const int wr = w >> 1, wc = w & 1;
    const int il = l & 15, kq = l >> 4;
    #pragma unroll
    for (int ni = 0; ni < 4; ++ni) {
        const int n = n0 + wc * 64 + ni * 16 + il;
        const float bb = b0[n];
        #pragma unroll
        for (int mi = 0; mi < 4; ++mi) {
            const int mbase = m0 + wr * 64 + mi * 16 + kq * 4;
            #pragma unroll
            for (int r = 0; r < 4; ++r) {
                const size_t idx = (size_t)(mbase + r) * E_DIM + n;
                out[idx] = acc[mi][ni][r] + bb + x[idx];
            }
        }
    }
}

// ----------------------------------------------------------------- launch
extern "C" void kernel_launch(void* const* d_in, const int* in_sizes, int n_in,
                              void* d_out, int out_size, void* d_ws, size_t ws_size,
                              hipStream_t stream) {
    (void)in_sizes; (void)n_in; (void)out_size; (void)ws_size;
    const float* x    = (const float*)d_in[0];
    const float* ln_g = (const float*)d_in[1];
    const float* ln_b = (const float*)d_in[2];
    const float* wq   = (const float*)d_in[3];
    const float* bq   = (const float*)d_in[4];
    const float* wk   = (const float*)d_in[5];
    const float* bk   = (const float*)d_in[6];
    const float* wv   = (const float*)d_in[7];
    const float* bv   = (const float*)d_in[8];
    const float* w0   = (const float*)d_in[9];
    const float* b0   = (const float*)d_in[10];

    uint8_t* ws = (uint8_t*)d_ws;
    unsigned short* xnb = (unsigned short*)(ws);                 // 8 MB (reused as hb)
    unsigned short* qb  = (unsigned short*)(ws + (8u  << 20));   // 8 MB
    unsigned short* kb  = (unsigned short*)(ws + (16u << 20));   // 8 MB
    unsigned short* vtb = (unsigned short*)(ws + (24u << 20));   // 8 MB (V^T)
    unsigned short* wqT = (unsigned short*)(ws + (32u << 20));   // 2 MB
    unsigned short* wkT = (unsigned short*)(ws + (34u << 20));
    unsigned short* wvT = (unsigned short*)(ws + (36u << 20));
    unsigned short* w0T = (unsigned short*)(ws + (38u << 20));
    unsigned short* hbf = xnb;   // xn is dead after qkv_kernel; alias to cut footprint

    hipLaunchKernelGGL(wtrans_kernel, dim3(16, 16, 4), dim3(256), 0, stream,
                       wq, wk, wv, w0, wqT, wkT, wvT, w0T);
    hipLaunchKernelGGL(ln_kernel, dim3(NROWS), dim3(256), 0, stream, x, ln_g, ln_b, xnb);
    hipLaunchKernelGGL(qkv_kernel, dim3(32, 8, 3), dim3(256), 0, stream,
                       xnb, wqT, bq, wkT, bk, wvT, bv, qb, kb, vtb);
    hipLaunchKernelGGL(attn_kernel, dim3(32, 32), dim3(256), 0, stream, qb, kb, vtb, hbf);
    hipLaunchKernelGGL(oproj_kernel, dim3(32, 8), dim3(256), 0, stream,
                       hbf, w0T, b0, x, (float*)d_out);
}

// Round 6
// 270.059 us; speedup vs baseline: 1.4512x; 1.4512x over previous
//
#include <hip/hip_runtime.h>
#include <hip/hip_bf16.h>
#include <stdint.h>

#define S_LEN 2048
#define E_DIM 1024
#define NHEAD 16
#define DHEAD 64
#define NB 2
#define NROWS (NB * S_LEN)   // 4096

typedef __attribute__((ext_vector_type(8))) short bf16x8;
typedef __attribute__((ext_vector_type(4))) float f32x4;

__device__ __forceinline__ unsigned short f2b(float f) {
    union { __hip_bfloat16 h; unsigned short u; } cv;
    cv.h = __float2bfloat16(f);
    return cv.u;
}

// async global->LDS, 16B per lane. LDS dest is wave-uniform base + lane*16.
__device__ __forceinline__ void gload_lds16(const void* g, void* l) {
    __builtin_amdgcn_global_load_lds(
        (const __attribute__((address_space(1))) unsigned int*)g,
        (__attribute__((address_space(3))) unsigned int*)l, 16, 0, 0);
}

// ------------------------------------------------ weight fp32[k][n] -> bf16 WT[n][k]
__global__ __launch_bounds__(256) void wtrans_kernel(
    const float* __restrict__ wq, const float* __restrict__ wk,
    const float* __restrict__ wv, const float* __restrict__ w0,
    unsigned short* __restrict__ wqT, unsigned short* __restrict__ wkT,
    unsigned short* __restrict__ wvT, unsigned short* __restrict__ w0T) {
    const int z = blockIdx.z;
    const float* W = (z == 0) ? wq : (z == 1) ? wk : (z == 2) ? wv : w0;
    unsigned short* WT = (z == 0) ? wqT : (z == 1) ? wkT : (z == 2) ? wvT : w0T;
    const int k0 = blockIdx.x * 64;
    const int n0 = blockIdx.y * 64;
    __shared__ float tile[64][69];   // 69: bank-spread for column reads
    const int t = threadIdx.x;
    const int rowq = t >> 4;          // 0..15
    const int cc4 = (t & 15) * 4;
    #pragma unroll
    for (int rr = 0; rr < 4; ++rr) {
        const int r = rr * 16 + rowq;
        const float4 v = *reinterpret_cast<const float4*>(W + (size_t)(k0 + r) * E_DIM + n0 + cc4);
        tile[r][cc4 + 0] = v.x; tile[r][cc4 + 1] = v.y;
        tile[r][cc4 + 2] = v.z; tile[r][cc4 + 3] = v.w;
    }
    __syncthreads();
    #pragma unroll
    for (int rr = 0; rr < 4; ++rr) {
        const int n = rr * 16 + rowq;
        ushort4 o;
        o.x = f2b(tile[cc4 + 0][n]);
        o.y = f2b(tile[cc4 + 1][n]);
        o.z = f2b(tile[cc4 + 2][n]);
        o.w = f2b(tile[cc4 + 3][n]);
        *reinterpret_cast<ushort4*>(WT + (size_t)(n0 + n) * E_DIM + k0 + cc4) = o;
    }
}

// ------------------------------------------------ LayerNorm -> bf16
__global__ __launch_bounds__(256) void ln_kernel(const float* __restrict__ x,
    const float* __restrict__ g, const float* __restrict__ bt,
    unsigned short* __restrict__ xn) {
    const int row = blockIdx.x;
    const int t = threadIdx.x;
    const float4 v = reinterpret_cast<const float4*>(x + (size_t)row * E_DIM)[t];
    float s  = v.x + v.y + v.z + v.w;
    float ss = v.x * v.x + v.y * v.y + v.z * v.z + v.w * v.w;
    #pragma unroll
    for (int off = 32; off > 0; off >>= 1) {
        s  += __shfl_down(s, off);
        ss += __shfl_down(ss, off);
    }
    __shared__ float red[8];
    if ((t & 63) == 0) { red[t >> 6] = s; red[(t >> 6) + 4] = ss; }
    __syncthreads();
    s  = red[0] + red[1] + red[2] + red[3];
    ss = red[4] + red[5] + red[6] + red[7];
    const float mu  = s * (1.0f / E_DIM);
    const float var = ss * (1.0f / E_DIM) - mu * mu;
    const float rs  = rsqrtf(var + 1e-5f);
    const float4 gv = reinterpret_cast<const float4*>(g)[t];
    const float4 bv = reinterpret_cast<const float4*>(bt)[t];
    ushort4 o;
    o.x = f2b((v.x - mu) * rs * gv.x + bv.x);
    o.y = f2b((v.y - mu) * rs * gv.y + bv.y);
    o.z = f2b((v.z - mu) * rs * gv.z + bv.z);
    o.w = f2b((v.w - mu) * rs * gv.w + bv.w);
    reinterpret_cast<ushort4*>(xn + (size_t)row * E_DIM)[t] = o;
}

// ------------------------------------------------ shared 128x128xK mainloop
// A [M][1024] bf16 row-major, BT [N][1024] bf16 row-major (= B^T).
// LDS tiles [128][64] with 16B-slot XOR swizzle: LDS(row, s) = global(row, s ^ (row&7)).
__device__ __forceinline__ void gemm128_mainloop(
    const unsigned short* __restrict__ A, const unsigned short* __restrict__ BT,
    int m0, int n0, unsigned short* As, unsigned short* Bs, f32x4 acc[4][4]) {
    const int t = threadIdx.x;
    const int l = t & 63;
    const int w = t >> 6;
    const int wr = w >> 1, wc = w & 1;
    const int lr = l >> 3;          // row within 8-row staging chunk
    const int gs = (l & 7) ^ lr;    // pre-swizzled source slot
    const int il = l & 15;          // fragment row
    const int kq = l >> 4;          // k quarter

    for (int kt = 0; kt < E_DIM; kt += 64) {
        __syncthreads();            // previous tile's reads done
        #pragma unroll
        for (int c = 0; c < 4; ++c) {
            const int cc = w * 4 + c;
            gload_lds16(A + (size_t)(m0 + cc * 8 + lr) * E_DIM + kt + gs * 8, As + cc * 512);
        }
        #pragma unroll
        for (int c = 0; c < 4; ++c) {
            const int cc = w * 4 + c;
            gload_lds16(BT + (size_t)(n0 + cc * 8 + lr) * E_DIM + kt + gs * 8, Bs + cc * 512);
        }
        __syncthreads();            // drains vmcnt -> tile ready
        #pragma unroll
        for (int ks = 0; ks < 2; ++ks) {
            bf16x8 af[4], bfr[4];
            #pragma unroll
            for (int mi = 0; mi < 4; ++mi) {
                const int r = wr * 64 + mi * 16 + il;
                af[mi] = *reinterpret_cast<const bf16x8*>(As + r * 64 + ((ks * 4 + kq) ^ (r & 7)) * 8);
            }
            #pragma unroll
            for (int ni = 0; ni < 4; ++ni) {
                const int r = wc * 64 + ni * 16 + il;
                bfr[ni] = *reinterpret_cast<const bf16x8*>(Bs + r * 64 + ((ks * 4 + kq) ^ (r & 7)) * 8);
            }
            #pragma unroll
            for (int mi = 0; mi < 4; ++mi)
                #pragma unroll
                for (int ni = 0; ni < 4; ++ni)
                    acc[mi][ni] = __builtin_amdgcn_mfma_f32_16x16x32_bf16(af[mi], bfr[ni], acc[mi][ni], 0, 0, 0);
        }
    }
}

// ------------------------------------------------ QKV projection
// q: [b,h,s,d] bf16 pre-scaled by 1/8; k: [b,h,s,d] bf16; v: TRANSPOSED [b,h,d,s] bf16.
__global__ __launch_bounds__(256) void qkv_kernel(
    const unsigned short* __restrict__ xn,
    const unsigned short* __restrict__ wqT, const float* __restrict__ bq,
    const unsigned short* __restrict__ wkT, const float* __restrict__ bk,
    const unsigned short* __restrict__ wvT, const float* __restrict__ bv,
    unsigned short* __restrict__ qo, unsigned short* __restrict__ ko,
    unsigned short* __restrict__ vo) {
    __shared__ __align__(16) unsigned short As[8192];
    __shared__ __align__(16) unsigned short Bs[8192];
    const int mat = blockIdx.z;
    const unsigned short* BT = (mat == 0) ? wqT : (mat == 1) ? wkT : wvT;
    const float* bias = (mat == 0) ? bq : (mat == 1) ? bk : bv;
    const int m0 = blockIdx.x * 128, n0 = blockIdx.y * 128;

    const f32x4 ZERO = {0.f, 0.f, 0.f, 0.f};
    f32x4 acc[4][4];
    #pragma unroll
    for (int i = 0; i < 4; ++i)
        #pragma unroll
        for (int j = 0; j < 4; ++j) acc[i][j] = ZERO;

    gemm128_mainloop(xn, BT, m0, n0, As, Bs, acc);

    const int t = threadIdx.x, l = t & 63, w = t >> 6;
    const int wr = w >> 1, wc = w & 1;
    const int il = l & 15, kq = l >> 4;
    const int b = m0 >> 11;
    const float qsc = (mat == 0) ? 0.125f : 1.0f;
    unsigned short* outp = (mat == 0) ? qo : ko;

    #pragma unroll
    for (int ni = 0; ni < 4; ++ni) {
        const int n = n0 + wc * 64 + ni * 16 + il;
        const int h = n >> 6, d = n & 63;
        const float bb = bias[n];
        #pragma unroll
        for (int mi = 0; mi < 4; ++mi) {
            const int mbase = m0 + wr * 64 + mi * 16 + kq * 4;
            const int sbase = mbase & (S_LEN - 1);
            if (mat == 2) {
                ushort4 o;
                o.x = f2b(acc[mi][ni][0] + bb);
                o.y = f2b(acc[mi][ni][1] + bb);
                o.z = f2b(acc[mi][ni][2] + bb);
                o.w = f2b(acc[mi][ni][3] + bb);
                *reinterpret_cast<ushort4*>(vo + ((size_t)(b * NHEAD + h) * DHEAD + d) * S_LEN + sbase) = o;
            } else {
                #pragma unroll
                for (int r = 0; r < 4; ++r)
                    outp[((size_t)(b * NHEAD + h) * S_LEN + sbase + r) * DHEAD + d] =
                        f2b((acc[mi][ni][r] + bb) * qsc);
            }
        }
    }
}

// ------------------------------------------------ flash attention (mask: attend j >= i)
// 2-phase double-buffered K/V staging (T3 minimum recipe): stage(next) is issued
// BEFORE compute(cur); the single trailing __syncthreads() (implicit vmcnt drain)
// is overlapped by the whole compute phase. One barrier per KV tile.
__global__ __launch_bounds__(256) void attn_kernel(
    const unsigned short* __restrict__ q,    // [bh][s][d], pre-scaled
    const unsigned short* __restrict__ k,    // [bh][s][d]
    const unsigned short* __restrict__ vt,   // [bh][d][s]
    unsigned short* __restrict__ hb) {       // [4096][1024] bf16
    __shared__ __align__(16) unsigned short Ks[2][4096];
    __shared__ __align__(16) unsigned short Vs[2][4096];
    __shared__ __align__(16) unsigned short Ps[4096];
    const int qi0 = blockIdx.x * 64;
    const int bh = blockIdx.y;
    const unsigned short* qp = q + (size_t)bh * S_LEN * DHEAD;
    const unsigned short* kp = k + (size_t)bh * S_LEN * DHEAD;
    const unsigned short* vp = vt + (size_t)bh * DHEAD * S_LEN;
    const int t = threadIdx.x, l = t & 63, w = t >> 6;
    const int il = l & 15, kq = l >> 4;
    const int lr = l >> 3, gs = (l & 7) ^ lr;

    auto stage_kv = [&](int buf, int kt) {
        #pragma unroll
        for (int c = 0; c < 2; ++c) {
            const int cc = w * 2 + c;
            const int row = cc * 8 + lr;
            gload_lds16(kp + (size_t)(kt + row) * DHEAD + gs * 8, &Ks[buf][cc * 512]);
            gload_lds16(vp + (size_t)row * S_LEN + kt + gs * 8, &Vs[buf][cc * 512]);
        }
    };

    const f32x4 ZERO = {0.f, 0.f, 0.f, 0.f};
    bf16x8 qf[2];
    const int qrow = qi0 + w * 16 + il;
    qf[0] = *reinterpret_cast<const bf16x8*>(qp + (size_t)qrow * DHEAD + kq * 8);
    qf[1] = *reinterpret_cast<const bf16x8*>(qp + (size_t)qrow * DHEAD + 32 + kq * 8);

    float m[4], lsum[4];
    f32x4 o[4];
    #pragma unroll
    for (int r = 0; r < 4; ++r) { m[r] = -INFINITY; lsum[r] = 0.f; }
    #pragma unroll
    for (int nf = 0; nf < 4; ++nf) o[nf] = ZERO;

    unsigned short* Pw = Ps + w * 1024;   // per-wave 16x64 P tile

    // prologue: stage first tile into buf 0
    stage_kv(0, qi0);
    __syncthreads();
    int cur = 0;

    for (int kt0 = qi0; kt0 < S_LEN; kt0 += 64) {
        if (kt0 + 64 < S_LEN) stage_kv(cur ^ 1, kt0 + 64);   // issue next-tile loads early
        const unsigned short* Kc = Ks[cur];
        const unsigned short* Vc = Vs[cur];

        f32x4 s[4];
        #pragma unroll
        for (int nf = 0; nf < 4; ++nf) s[nf] = ZERO;
        #pragma unroll
        for (int ks = 0; ks < 2; ++ks)
            #pragma unroll
            for (int nf = 0; nf < 4; ++nf) {
                const int j = nf * 16 + il;
                const bf16x8 kf = *reinterpret_cast<const bf16x8*>(Kc + j * 64 + ((ks * 4 + kq) ^ (j & 7)) * 8);
                s[nf] = __builtin_amdgcn_mfma_f32_16x16x32_bf16(qf[ks], kf, s[nf], 0, 0, 0);
            }

        if (kt0 == qi0) {   // diagonal tile: mask j < i
            #pragma unroll
            for (int nf = 0; nf < 4; ++nf) {
                const int j = kt0 + nf * 16 + il;
                #pragma unroll
                for (int r = 0; r < 4; ++r) {
                    const int i = qi0 + w * 16 + kq * 4 + r;
                    if (j < i) s[nf][r] = -INFINITY;
                }
            }
        }

        // online softmax (16-lane row groups: il varies, kq fixed)
        float tm[4];
        #pragma unroll
        for (int r = 0; r < 4; ++r)
            tm[r] = fmaxf(fmaxf(s[0][r], s[1][r]), fmaxf(s[2][r], s[3][r]));
        #pragma unroll
        for (int msk = 8; msk; msk >>= 1)
            #pragma unroll
            for (int r = 0; r < 4; ++r)
                tm[r] = fmaxf(tm[r], __shfl_xor(tm[r], msk));

        float sc_[4];
        #pragma unroll
        for (int r = 0; r < 4; ++r) {
            const float nm = fmaxf(m[r], tm[r]);
            sc_[r] = __expf(m[r] - nm);
            m[r] = nm;
        }

        float ps[4] = {0.f, 0.f, 0.f, 0.f};
        #pragma unroll
        for (int nf = 0; nf < 4; ++nf)
            #pragma unroll
            for (int r = 0; r < 4; ++r) {
                const float pv = __expf(s[nf][r] - m[r]);
                ps[r] += pv;
                const int i = kq * 4 + r;
                const int col = nf * 16 + il;
                Pw[i * 64 + (((col >> 3) ^ (i & 7)) * 8) + (col & 7)] = f2b(pv);
            }
        #pragma unroll
        for (int msk = 8; msk; msk >>= 1)
            #pragma unroll
            for (int r = 0; r < 4; ++r)
                ps[r] += __shfl_xor(ps[r], msk);
        #pragma unroll
        for (int r = 0; r < 4; ++r) lsum[r] = lsum[r] * sc_[r] + ps[r];
        #pragma unroll
        for (int nf = 0; nf < 4; ++nf)
            #pragma unroll
            for (int r = 0; r < 4; ++r) o[nf][r] *= sc_[r];

        asm volatile("s_waitcnt lgkmcnt(0)" ::: "memory");   // own-wave P writes visible
        #pragma unroll
        for (int ks = 0; ks < 2; ++ks) {
            const bf16x8 pa = *reinterpret_cast<const bf16x8*>(Pw + il * 64 + ((ks * 4 + kq) ^ (il & 7)) * 8);
            #pragma unroll
            for (int nf = 0; nf < 4; ++nf) {
                const int dl = nf * 16 + il;
                const bf16x8 vf = *reinterpret_cast<const bf16x8*>(Vc + dl * 64 + ((ks * 4 + kq) ^ (dl & 7)) * 8);
                o[nf] = __builtin_amdgcn_mfma_f32_16x16x32_bf16(pa, vf, o[nf], 0, 0, 0);
            }
        }

        __syncthreads();   // drains vmcnt (next tile staged) + protects buf reuse
        cur ^= 1;
    }

    const int b = bh >> 4, hh = bh & 15;
    float rl[4];
    #pragma unroll
    for (int r = 0; r < 4; ++r) rl[r] = 1.0f / lsum[r];
    #pragma unroll
    for (int nf = 0; nf < 4; ++nf) {
        const int col = hh * 64 + nf * 16 + il;
        #pragma unroll
        for (int r = 0; r < 4; ++r) {
            const int srow = qi0 + w * 16 + kq * 4 + r;
            hb[(size_t)(b * S_LEN + srow) * E_DIM + col] = f2b(o[nf][r] * rl[r]);
        }
    }
}

// ------------------------------------------------ output proj + bias + residual
__global__ __launch_bounds__(256) void oproj_kernel(
    const unsigned short* __restrict__ hbuf, const unsigned short* __restrict__ w0T,
    const float* __restrict__ b0, const float* __restrict__ x,
    float* __restrict__ out) {
    __shared__ __align__(16) unsigned short As[8192];
    __shared__ __align__(16) unsigned short Bs[8192];
    const int m0 = blockIdx.x * 128, n0 = blockIdx.y * 128;

    const f32x4 ZERO = {0.f, 0.f, 0.f, 0.f};
    f32x4 acc[4][4];
    #pragma unroll
    for (int i = 0; i < 4; ++i)
        #pragma unroll
        for (int j = 0; j < 4; ++j) acc[i][j] = ZERO;

    gemm128_mainloop(hbuf, w0T, m0, n0, As, Bs, acc);

    const int t = threadIdx.x, l = t & 63, w = t >> 6;
    const int wr = w >> 1, wc = w & 1;
    const int il = l & 15, kq = l >> 4;
    #pragma unroll
    for (int ni = 0; ni < 4; ++ni) {
        const int n = n0 + wc * 64 + ni * 16 + il;
        const float bb = b0[n];
        #pragma unroll
        for (int mi = 0; mi < 4; ++mi) {
            const int mbase = m0 + wr * 64 + mi * 16 + kq * 4;
            #pragma unroll
            for (int r = 0; r < 4; ++r) {
                const size_t idx = (size_t)(mbase + r) * E_DIM + n;
                out[idx] = acc[mi][ni][r] + bb + x[idx];
            }
        }
    }
}

// ----------------------------------------------------------------- launch
extern "C" void kernel_launch(void* const* d_in, const int* in_sizes, int n_in,
                              void* d_out, int out_size, void* d_ws, size_t ws_size,
                              hipStream_t stream) {
    (void)in_sizes; (void)n_in; (void)out_size; (void)ws_size;
    const float* x    = (const float*)d_in[0];
    const float* ln_g = (const float*)d_in[1];
    const float* ln_b = (const float*)d_in[2];
    const float* wq   = (const float*)d_in[3];
    const float* bq   = (const float*)d_in[4];
    const float* wk   = (const float*)d_in[5];
    const float* bk   = (const float*)d_in[6];
    const float* wv   = (const float*)d_in[7];
    const float* bv   = (const float*)d_in[8];
    const float* w0   = (const float*)d_in[9];
    const float* b0   = (const float*)d_in[10];

    uint8_t* ws = (uint8_t*)d_ws;
    unsigned short* xnb = (unsigned short*)(ws);                 // 8 MB (reused as hb)
    unsigned short* qb  = (unsigned short*)(ws + (8u  << 20));   // 8 MB
    unsigned short* kb  = (unsigned short*)(ws + (16u << 20));   // 8 MB
    unsigned short* vtb = (unsigned short*)(ws + (24u << 20));   // 8 MB (V^T)
    unsigned short* wqT = (unsigned short*)(ws + (32u << 20));   // 2 MB
    unsigned short* wkT = (unsigned short*)(ws + (34u << 20));
    unsigned short* wvT = (unsigned short*)(ws + (36u << 20));
    unsigned short* w0T = (unsigned short*)(ws + (38u << 20));
    unsigned short* hbf = xnb;   // xn is dead after qkv_kernel; alias to cut footprint

    hipLaunchKernelGGL(wtrans_kernel, dim3(16, 16, 4), dim3(256), 0, stream,
                       wq, wk, wv, w0, wqT, wkT, wvT, w0T);
    hipLaunchKernelGGL(ln_kernel, dim3(NROWS), dim3(256), 0, stream, x, ln_g, ln_b, xnb);
    hipLaunchKernelGGL(qkv_kernel, dim3(32, 8, 3), dim3(256), 0, stream,
                       xnb, wqT, bq, wkT, bk, wvT, bv, qb, kb, vtb);
    hipLaunchKernelGGL(attn_kernel, dim3(32, 32), dim3(256), 0, stream, qb, kb, vtb, hbf);
    hipLaunchKernelGGL(oproj_kernel, dim3(32, 8), dim3(256), 0, stream,
                       hbf, w0T, b0, x, (float*)d_out);
}

// Round 7
// 248.064 us; speedup vs baseline: 1.5799x; 1.0887x over previous
//
#include <hip/hip_runtime.h>
#include <hip/hip_bf16.h>
#include <stdint.h>

#define S_LEN 2048
#define E_DIM 1024
#define NHEAD 16
#define DHEAD 64
#define NB 2
#define NROWS (NB * S_LEN)   // 4096

typedef __attribute__((ext_vector_type(8))) short bf16x8;
typedef __attribute__((ext_vector_type(4))) float f32x4;

__device__ __forceinline__ unsigned short f2b(float f) {
    union { __hip_bfloat16 h; unsigned short u; } cv;
    cv.h = __float2bfloat16(f);
    return cv.u;
}

// async global->LDS, 16B per lane. LDS dest is wave-uniform base + lane*16.
__device__ __forceinline__ void gload_lds16(const void* g, void* l) {
    __builtin_amdgcn_global_load_lds(
        (const __attribute__((address_space(1))) unsigned int*)g,
        (__attribute__((address_space(3))) unsigned int*)l, 16, 0, 0);
}

// ------------------------------------------------ weight fp32[k][n] -> bf16 WT[n][k]
__global__ __launch_bounds__(256) void wtrans_kernel(
    const float* __restrict__ wq, const float* __restrict__ wk,
    const float* __restrict__ wv, const float* __restrict__ w0,
    unsigned short* __restrict__ wqT, unsigned short* __restrict__ wkT,
    unsigned short* __restrict__ wvT, unsigned short* __restrict__ w0T) {
    const int z = blockIdx.z;
    const float* W = (z == 0) ? wq : (z == 1) ? wk : (z == 2) ? wv : w0;
    unsigned short* WT = (z == 0) ? wqT : (z == 1) ? wkT : (z == 2) ? wvT : w0T;
    const int k0 = blockIdx.x * 64;
    const int n0 = blockIdx.y * 64;
    __shared__ float tile[64][69];   // 69: bank-spread for column reads
    const int t = threadIdx.x;
    const int rowq = t >> 4;          // 0..15
    const int cc4 = (t & 15) * 4;
    #pragma unroll
    for (int rr = 0; rr < 4; ++rr) {
        const int r = rr * 16 + rowq;
        const float4 v = *reinterpret_cast<const float4*>(W + (size_t)(k0 + r) * E_DIM + n0 + cc4);
        tile[r][cc4 + 0] = v.x; tile[r][cc4 + 1] = v.y;
        tile[r][cc4 + 2] = v.z; tile[r][cc4 + 3] = v.w;
    }
    __syncthreads();
    #pragma unroll
    for (int rr = 0; rr < 4; ++rr) {
        const int n = rr * 16 + rowq;
        ushort4 o;
        o.x = f2b(tile[cc4 + 0][n]);
        o.y = f2b(tile[cc4 + 1][n]);
        o.z = f2b(tile[cc4 + 2][n]);
        o.w = f2b(tile[cc4 + 3][n]);
        *reinterpret_cast<ushort4*>(WT + (size_t)(n0 + n) * E_DIM + k0 + cc4) = o;
    }
}

// ------------------------------------------------ LayerNorm -> bf16
__global__ __launch_bounds__(256) void ln_kernel(const float* __restrict__ x,
    const float* __restrict__ g, const float* __restrict__ bt,
    unsigned short* __restrict__ xn) {
    const int row = blockIdx.x;
    const int t = threadIdx.x;
    const float4 v = reinterpret_cast<const float4*>(x + (size_t)row * E_DIM)[t];
    float s  = v.x + v.y + v.z + v.w;
    float ss = v.x * v.x + v.y * v.y + v.z * v.z + v.w * v.w;
    #pragma unroll
    for (int off = 32; off > 0; off >>= 1) {
        s  += __shfl_down(s, off);
        ss += __shfl_down(ss, off);
    }
    __shared__ float red[8];
    if ((t & 63) == 0) { red[t >> 6] = s; red[(t >> 6) + 4] = ss; }
    __syncthreads();
    s  = red[0] + red[1] + red[2] + red[3];
    ss = red[4] + red[5] + red[6] + red[7];
    const float mu  = s * (1.0f / E_DIM);
    const float var = ss * (1.0f / E_DIM) - mu * mu;
    const float rs  = rsqrtf(var + 1e-5f);
    const float4 gv = reinterpret_cast<const float4*>(g)[t];
    const float4 bv = reinterpret_cast<const float4*>(bt)[t];
    ushort4 o;
    o.x = f2b((v.x - mu) * rs * gv.x + bv.x);
    o.y = f2b((v.y - mu) * rs * gv.y + bv.y);
    o.z = f2b((v.z - mu) * rs * gv.z + bv.z);
    o.w = f2b((v.w - mu) * rs * gv.w + bv.w);
    reinterpret_cast<ushort4*>(xn + (size_t)row * E_DIM)[t] = o;
}

// ------------------------------------------------ shared 128x128xK mainloop
__device__ __forceinline__ void gemm128_mainloop(
    const unsigned short* __restrict__ A, const unsigned short* __restrict__ BT,
    int m0, int n0, unsigned short* As, unsigned short* Bs, f32x4 acc[4][4]) {
    const int t = threadIdx.x;
    const int l = t & 63;
    const int w = t >> 6;
    const int wr = w >> 1, wc = w & 1;
    const int lr = l >> 3;          // row within 8-row staging chunk
    const int gs = (l & 7) ^ lr;    // pre-swizzled source slot
    const int il = l & 15;          // fragment row
    const int kq = l >> 4;          // k quarter

    for (int kt = 0; kt < E_DIM; kt += 64) {
        __syncthreads();            // previous tile's reads done
        #pragma unroll
        for (int c = 0; c < 4; ++c) {
            const int cc = w * 4 + c;
            gload_lds16(A + (size_t)(m0 + cc * 8 + lr) * E_DIM + kt + gs * 8, As + cc * 512);
        }
        #pragma unroll
        for (int c = 0; c < 4; ++c) {
            const int cc = w * 4 + c;
            gload_lds16(BT + (size_t)(n0 + cc * 8 + lr) * E_DIM + kt + gs * 8, Bs + cc * 512);
        }
        __syncthreads();            // drains vmcnt -> tile ready
        #pragma unroll
        for (int ks = 0; ks < 2; ++ks) {
            bf16x8 af[4], bfr[4];
            #pragma unroll
            for (int mi = 0; mi < 4; ++mi) {
                const int r = wr * 64 + mi * 16 + il;
                af[mi] = *reinterpret_cast<const bf16x8*>(As + r * 64 + ((ks * 4 + kq) ^ (r & 7)) * 8);
            }
            #pragma unroll
            for (int ni = 0; ni < 4; ++ni) {
                const int r = wc * 64 + ni * 16 + il;
                bfr[ni] = *reinterpret_cast<const bf16x8*>(Bs + r * 64 + ((ks * 4 + kq) ^ (r & 7)) * 8);
            }
            #pragma unroll
            for (int mi = 0; mi < 4; ++mi)
                #pragma unroll
                for (int ni = 0; ni < 4; ++ni)
                    acc[mi][ni] = __builtin_amdgcn_mfma_f32_16x16x32_bf16(af[mi], bfr[ni], acc[mi][ni], 0, 0, 0);
        }
    }
}

// ------------------------------------------------ QKV projection
__global__ __launch_bounds__(256) void qkv_kernel(
    const unsigned short* __restrict__ xn,
    const unsigned short* __restrict__ wqT, const float* __restrict__ bq,
    const unsigned short* __restrict__ wkT, const float* __restrict__ bk,
    const unsigned short* __restrict__ wvT, const float* __restrict__ bv,
    unsigned short* __restrict__ qo, unsigned short* __restrict__ ko,
    unsigned short* __restrict__ vo) {
    __shared__ __align__(16) unsigned short As[8192];
    __shared__ __align__(16) unsigned short Bs[8192];
    const int mat = blockIdx.z;
    const unsigned short* BT = (mat == 0) ? wqT : (mat == 1) ? wkT : wvT;
    const float* bias = (mat == 0) ? bq : (mat == 1) ? bk : bv;
    const int m0 = blockIdx.x * 128, n0 = blockIdx.y * 128;

    const f32x4 ZERO = {0.f, 0.f, 0.f, 0.f};
    f32x4 acc[4][4];
    #pragma unroll
    for (int i = 0; i < 4; ++i)
        #pragma unroll
        for (int j = 0; j < 4; ++j) acc[i][j] = ZERO;

    gemm128_mainloop(xn, BT, m0, n0, As, Bs, acc);

    const int t = threadIdx.x, l = t & 63, w = t >> 6;
    const int wr = w >> 1, wc = w & 1;
    const int il = l & 15, kq = l >> 4;
    const int b = m0 >> 11;
    const float qsc = (mat == 0) ? 0.125f : 1.0f;
    unsigned short* outp = (mat == 0) ? qo : ko;

    #pragma unroll
    for (int ni = 0; ni < 4; ++ni) {
        const int n = n0 + wc * 64 + ni * 16 + il;
        const int h = n >> 6, d = n & 63;
        const float bb = bias[n];
        #pragma unroll
        for (int mi = 0; mi < 4; ++mi) {
            const int mbase = m0 + wr * 64 + mi * 16 + kq * 4;
            const int sbase = mbase & (S_LEN - 1);
            if (mat == 2) {
                ushort4 o;
                o.x = f2b(acc[mi][ni][0] + bb);
                o.y = f2b(acc[mi][ni][1] + bb);
                o.z = f2b(acc[mi][ni][2] + bb);
                o.w = f2b(acc[mi][ni][3] + bb);
                *reinterpret_cast<ushort4*>(vo + ((size_t)(b * NHEAD + h) * DHEAD + d) * S_LEN + sbase) = o;
            } else {
                #pragma unroll
                for (int r = 0; r < 4; ++r)
                    outp[((size_t)(b * NHEAD + h) * S_LEN + sbase + r) * DHEAD + d] =
                        f2b((acc[mi][ni][r] + bb) * qsc);
            }
        }
    }
}

// ------------------------------------------------ flash attention tile (128 KV)
// Kc: [128 rows][8 slots of 16B], slot s holds global slot s^(row&7).
// Vc: [64 d-rows][16 slots], slot s holds global slot s^(row&15).
// Pw: per-wave [16 q-rows][128 cols], swizzle slot^(row).
__device__ __forceinline__ void attn_tile128(
    const unsigned short* __restrict__ Kc, const unsigned short* __restrict__ Vc,
    unsigned short* __restrict__ Pw, const bf16x8* qf,
    float* m, float* lsum, f32x4* o,
    int il, int kq, int w, int qi0, int kt0, bool do_mask) {
    const f32x4 ZERO = {0.f, 0.f, 0.f, 0.f};
    f32x4 s[8];
    #pragma unroll
    for (int nf = 0; nf < 8; ++nf) s[nf] = ZERO;
    #pragma unroll
    for (int ks = 0; ks < 2; ++ks)
        #pragma unroll
        for (int nf = 0; nf < 8; ++nf) {
            const int j = nf * 16 + il;
            const bf16x8 kf = *reinterpret_cast<const bf16x8*>(
                Kc + j * 64 + (((ks * 4 + kq) ^ (il & 7)) * 8));
            s[nf] = __builtin_amdgcn_mfma_f32_16x16x32_bf16(qf[ks], kf, s[nf], 0, 0, 0);
        }
    if (do_mask) {
        #pragma unroll
        for (int nf = 0; nf < 8; ++nf) {
            const int j = kt0 + nf * 16 + il;
            #pragma unroll
            for (int r = 0; r < 4; ++r) {
                const int i = qi0 + w * 16 + kq * 4 + r;
                if (j < i) s[nf][r] = -INFINITY;
            }
        }
    }
    float tm[4];
    #pragma unroll
    for (int r = 0; r < 4; ++r) {
        float v = s[0][r];
        #pragma unroll
        for (int nf = 1; nf < 8; ++nf) v = fmaxf(v, s[nf][r]);
        tm[r] = v;
    }
    #pragma unroll
    for (int msk = 8; msk; msk >>= 1)
        #pragma unroll
        for (int r = 0; r < 4; ++r)
            tm[r] = fmaxf(tm[r], __shfl_xor(tm[r], msk));
    float sc_[4];
    #pragma unroll
    for (int r = 0; r < 4; ++r) {
        const float nm = fmaxf(m[r], tm[r]);
        sc_[r] = __expf(m[r] - nm);
        m[r] = nm;
    }
    float ps[4] = {0.f, 0.f, 0.f, 0.f};
    #pragma unroll
    for (int nf = 0; nf < 8; ++nf)
        #pragma unroll
        for (int r = 0; r < 4; ++r) {
            const float pv = __expf(s[nf][r] - m[r]);
            ps[r] += pv;
            const int i = kq * 4 + r;
            const int col = nf * 16 + il;
            Pw[i * 128 + (((col >> 3) ^ i) * 8) + (col & 7)] = f2b(pv);
        }
    #pragma unroll
    for (int msk = 8; msk; msk >>= 1)
        #pragma unroll
        for (int r = 0; r < 4; ++r)
            ps[r] += __shfl_xor(ps[r], msk);
    #pragma unroll
    for (int r = 0; r < 4; ++r) lsum[r] = lsum[r] * sc_[r] + ps[r];
    #pragma unroll
    for (int nf = 0; nf < 4; ++nf)
        #pragma unroll
        for (int r = 0; r < 4; ++r) o[nf][r] *= sc_[r];
    asm volatile("s_waitcnt lgkmcnt(0)" ::: "memory");   // own-wave P writes visible
    #pragma unroll
    for (int ks = 0; ks < 4; ++ks) {
        const bf16x8 pa = *reinterpret_cast<const bf16x8*>(
            Pw + il * 128 + (((ks * 4 + kq) ^ il) * 8));
        #pragma unroll
        for (int nf = 0; nf < 4; ++nf) {
            const int dl = nf * 16 + il;
            const bf16x8 vf = *reinterpret_cast<const bf16x8*>(
                Vc + dl * 128 + (((ks * 4 + kq) ^ il) * 8));
            o[nf] = __builtin_amdgcn_mfma_f32_16x16x32_bf16(pa, vf, o[nf], 0, 0, 0);
        }
    }
}

// ------------------------------------------------ flash attention (mask: attend j >= i)
// PAIRED q-tiles for load balance: block does q-tile qtA and 31-qtA -> uniform
// 17 units of 128 KV per block. 512 blocks, 2/CU, no drain tail.
__global__ __launch_bounds__(256) void attn_kernel(
    const unsigned short* __restrict__ q,    // [bh][s][d], pre-scaled
    const unsigned short* __restrict__ k,    // [bh][s][d]
    const unsigned short* __restrict__ vt,   // [bh][d][s]
    unsigned short* __restrict__ hb) {       // [4096][1024] bf16
    __shared__ __align__(16) unsigned short Ks[2][8192];   // 128x64
    __shared__ __align__(16) unsigned short Vs[2][8192];   // 64x128
    __shared__ __align__(16) unsigned short Ps[8192];      // 4 waves x 16x128
    const int qtA = blockIdx.x;              // 0..15
    const int bh  = blockIdx.y;
    const int qiA = qtA * 64;
    const int qiB = (31 - qtA) * 64;
    const int startA = qiA & ~127;
    const int startB = qiB & ~127;
    const unsigned short* qp = q + (size_t)bh * S_LEN * DHEAD;
    const unsigned short* kp = k + (size_t)bh * S_LEN * DHEAD;
    const unsigned short* vp = vt + (size_t)bh * DHEAD * S_LEN;
    const int t = threadIdx.x, l = t & 63, w = t >> 6;
    const int il = l & 15, kq = l >> 4;
    const int lr = l >> 3, kls = l & 7;      // K staging: 8 rows x 8 slots
    const int vr = l >> 4, vs = l & 15;      // V staging: 4 rows x 16 slots

    auto stage = [&](int buf, int kt) {
        #pragma unroll
        for (int c = 0; c < 4; ++c) {
            const int cc = w * 4 + c;
            const int krow = cc * 8 + lr;
            gload_lds16(kp + (size_t)(kt + krow) * DHEAD + (kls ^ lr) * 8, &Ks[buf][cc * 512]);
            const int vrow = cc * 4 + vr;
            gload_lds16(vp + (size_t)vrow * S_LEN + kt + (vs ^ (vrow & 15)) * 8, &Vs[buf][cc * 512]);
        }
    };

    const f32x4 ZERO = {0.f, 0.f, 0.f, 0.f};
    bf16x8 qfA[2], qfB[2];
    {
        const int rA = qiA + w * 16 + il;
        const int rB = qiB + w * 16 + il;
        qfA[0] = *reinterpret_cast<const bf16x8*>(qp + (size_t)rA * DHEAD + kq * 8);
        qfA[1] = *reinterpret_cast<const bf16x8*>(qp + (size_t)rA * DHEAD + 32 + kq * 8);
        qfB[0] = *reinterpret_cast<const bf16x8*>(qp + (size_t)rB * DHEAD + kq * 8);
        qfB[1] = *reinterpret_cast<const bf16x8*>(qp + (size_t)rB * DHEAD + 32 + kq * 8);
    }

    float mA[4], lA[4], mB[4], lB[4];
    f32x4 oA[4], oB[4];
    #pragma unroll
    for (int r = 0; r < 4; ++r) { mA[r] = -INFINITY; lA[r] = 0.f; mB[r] = -INFINITY; lB[r] = 0.f; }
    #pragma unroll
    for (int nf = 0; nf < 4; ++nf) { oA[nf] = ZERO; oB[nf] = ZERO; }

    unsigned short* Pw = Ps + w * 2048;   // per-wave 16x128 P tile

    stage(0, startA);
    __syncthreads();
    int cur = 0;

    for (int kt0 = startA; kt0 < S_LEN; kt0 += 128) {
        if (kt0 + 128 < S_LEN) stage(cur ^ 1, kt0 + 128);
        attn_tile128(Ks[cur], Vs[cur], Pw, qfA, mA, lA, oA, il, kq, w, qiA, kt0, kt0 == startA);
        if (kt0 >= startB)
            attn_tile128(Ks[cur], Vs[cur], Pw, qfB, mB, lB, oB, il, kq, w, qiB, kt0, kt0 == startB);
        __syncthreads();   // drains vmcnt (next tile staged) + protects buf reuse
        cur ^= 1;
    }

    const int b = bh >> 4, hh = bh & 15;
    float rlA[4], rlB[4];
    #pragma unroll
    for (int r = 0; r < 4; ++r) { rlA[r] = 1.0f / lA[r]; rlB[r] = 1.0f / lB[r]; }
    #pragma unroll
    for (int nf = 0; nf < 4; ++nf) {
        const int col = hh * 64 + nf * 16 + il;
        #pragma unroll
        for (int r = 0; r < 4; ++r) {
            const int rowA = qiA + w * 16 + kq * 4 + r;
            const int rowB = qiB + w * 16 + kq * 4 + r;
            hb[(size_t)(b * S_LEN + rowA) * E_DIM + col] = f2b(oA[nf][r] * rlA[r]);
            hb[(size_t)(b * S_LEN + rowB) * E_DIM + col] = f2b(oB[nf][r] * rlB[r]);
        }
    }
}

// ------------------------------------------------ output proj + bias + residual
__global__ __launch_bounds__(256) void oproj_kernel(
    const unsigned short* __restrict__ hbuf, const unsigned short* __restrict__ w0T,
    const float* __restrict__ b0, const float* __restrict__ x,
    float* __restrict__ out) {
    __shared__ __align__(16) unsigned short As[8192];
    __shared__ __align__(16) unsigned short Bs[8192];
    const int m0 = blockIdx.x * 128, n0 = blockIdx.y * 128;

    const f32x4 ZERO = {0.f, 0.f, 0.f, 0.f};
    f32x4 acc[4][4];
    #pragma unroll
    for (int i = 0; i < 4; ++i)
        #pragma unroll
        for (int j = 0; j < 4; ++j) acc[i][j] = ZERO;

    gemm128_mainloop(hbuf, w0T, m0, n0, As, Bs, acc);

    const int t = threadIdx.x, l = t & 63, w = t >> 6;
    const int wr = w >> 1, wc = w & 1;
    const int il = l & 15, kq = l >> 4;
    #pragma unroll
    for (int ni = 0; ni < 4; ++ni) {
        const int n = n0 + wc * 64 + ni * 16 + il;
        const float bb = b0[n];
        #pragma unroll
        for (int mi = 0; mi < 4; ++mi) {
            const int mbase = m0 + wr * 64 + mi * 16 + kq * 4;
            #pragma unroll
            for (int r = 0; r < 4; ++r) {
                const size_t idx = (size_t)(mbase + r) * E_DIM + n;
                out[idx] = acc[mi][ni][r] + bb + x[idx];
            }
        }
    }
}

// ----------------------------------------------------------------- launch
extern "C" void kernel_launch(void* const* d_in, const int* in_sizes, int n_in,
                              void* d_out, int out_size, void* d_ws, size_t ws_size,
                              hipStream_t stream) {
    (void)in_sizes; (void)n_in; (void)out_size; (void)ws_size;
    const float* x    = (const float*)d_in[0];
    const float* ln_g = (const float*)d_in[1];
    const float* ln_b = (const float*)d_in[2];
    const float* wq   = (const float*)d_in[3];
    const float* bq   = (const float*)d_in[4];
    const float* wk   = (const float*)d_in[5];
    const float* bk   = (const float*)d_in[6];
    const float* wv   = (const float*)d_in[7];
    const float* bv   = (const float*)d_in[8];
    const float* w0   = (const float*)d_in[9];
    const float* b0   = (const float*)d_in[10];

    uint8_t* ws = (uint8_t*)d_ws;
    unsigned short* xnb = (unsigned short*)(ws);                 // 8 MB (reused as hb)
    unsigned short* qb  = (unsigned short*)(ws + (8u  << 20));   // 8 MB
    unsigned short* kb  = (unsigned short*)(ws + (16u << 20));   // 8 MB
    unsigned short* vtb = (unsigned short*)(ws + (24u << 20));   // 8 MB (V^T)
    unsigned short* wqT = (unsigned short*)(ws + (32u << 20));   // 2 MB
    unsigned short* wkT = (unsigned short*)(ws + (34u << 20));
    unsigned short* wvT = (unsigned short*)(ws + (36u << 20));
    unsigned short* w0T = (unsigned short*)(ws + (38u << 20));
    unsigned short* hbf = xnb;   // xn is dead after qkv_kernel; alias to cut footprint

    hipLaunchKernelGGL(wtrans_kernel, dim3(16, 16, 4), dim3(256), 0, stream,
                       wq, wk, wv, w0, wqT, wkT, wvT, w0T);
    hipLaunchKernelGGL(ln_kernel, dim3(NROWS), dim3(256), 0, stream, x, ln_g, ln_b, xnb);
    hipLaunchKernelGGL(qkv_kernel, dim3(32, 8, 3), dim3(256), 0, stream,
                       xnb, wqT, bq, wkT, bk, wvT, bv, qb, kb, vtb);
    hipLaunchKernelGGL(attn_kernel, dim3(16, 32), dim3(256), 0, stream, qb, kb, vtb, hbf);
    hipLaunchKernelGGL(oproj_kernel, dim3(32, 8), dim3(256), 0, stream,
                       hbf, w0T, b0, x, (float*)d_out);
}

// Round 8
// 213.969 us; speedup vs baseline: 1.8316x; 1.1593x over previous
//
#include <hip/hip_runtime.h>
#include <hip/hip_bf16.h>
#include <stdint.h>

#define S_LEN 2048
#define E_DIM 1024
#define NHEAD 16
#define DHEAD 64
#define NB 2
#define NROWS (NB * S_LEN)   // 4096

typedef __attribute__((ext_vector_type(8))) short bf16x8;
typedef __attribute__((ext_vector_type(4))) float f32x4;

__device__ __forceinline__ unsigned short f2b(float f) {
    union { __hip_bfloat16 h; unsigned short u; } cv;
    cv.h = __float2bfloat16(f);
    return cv.u;
}

// async global->LDS, 16B per lane. LDS dest is wave-uniform base + lane*16.
__device__ __forceinline__ void gload_lds16(const void* g, void* l) {
    __builtin_amdgcn_global_load_lds(
        (const __attribute__((address_space(1))) unsigned int*)g,
        (__attribute__((address_space(3))) unsigned int*)l, 16, 0, 0);
}

// ------------------------------------------------ weight fp32[k][n] -> bf16 WT[n][k]
__global__ __launch_bounds__(256) void wtrans_kernel(
    const float* __restrict__ wq, const float* __restrict__ wk,
    const float* __restrict__ wv, const float* __restrict__ w0,
    unsigned short* __restrict__ wqT, unsigned short* __restrict__ wkT,
    unsigned short* __restrict__ wvT, unsigned short* __restrict__ w0T) {
    const int z = blockIdx.z;
    const float* W = (z == 0) ? wq : (z == 1) ? wk : (z == 2) ? wv : w0;
    unsigned short* WT = (z == 0) ? wqT : (z == 1) ? wkT : (z == 2) ? wvT : w0T;
    const int k0 = blockIdx.x * 64;
    const int n0 = blockIdx.y * 64;
    __shared__ float tile[64][69];   // 69: bank-spread for column reads
    const int t = threadIdx.x;
    const int rowq = t >> 4;          // 0..15
    const int cc4 = (t & 15) * 4;
    #pragma unroll
    for (int rr = 0; rr < 4; ++rr) {
        const int r = rr * 16 + rowq;
        const float4 v = *reinterpret_cast<const float4*>(W + (size_t)(k0 + r) * E_DIM + n0 + cc4);
        tile[r][cc4 + 0] = v.x; tile[r][cc4 + 1] = v.y;
        tile[r][cc4 + 2] = v.z; tile[r][cc4 + 3] = v.w;
    }
    __syncthreads();
    #pragma unroll
    for (int rr = 0; rr < 4; ++rr) {
        const int n = rr * 16 + rowq;
        ushort4 o;
        o.x = f2b(tile[cc4 + 0][n]);
        o.y = f2b(tile[cc4 + 1][n]);
        o.z = f2b(tile[cc4 + 2][n]);
        o.w = f2b(tile[cc4 + 3][n]);
        *reinterpret_cast<ushort4*>(WT + (size_t)(n0 + n) * E_DIM + k0 + cc4) = o;
    }
}

// ------------------------------------------------ LayerNorm -> bf16
__global__ __launch_bounds__(256) void ln_kernel(const float* __restrict__ x,
    const float* __restrict__ g, const float* __restrict__ bt,
    unsigned short* __restrict__ xn) {
    const int row = blockIdx.x;
    const int t = threadIdx.x;
    const float4 v = reinterpret_cast<const float4*>(x + (size_t)row * E_DIM)[t];
    float s  = v.x + v.y + v.z + v.w;
    float ss = v.x * v.x + v.y * v.y + v.z * v.z + v.w * v.w;
    #pragma unroll
    for (int off = 32; off > 0; off >>= 1) {
        s  += __shfl_down(s, off);
        ss += __shfl_down(ss, off);
    }
    __shared__ float red[8];
    if ((t & 63) == 0) { red[t >> 6] = s; red[(t >> 6) + 4] = ss; }
    __syncthreads();
    s  = red[0] + red[1] + red[2] + red[3];
    ss = red[4] + red[5] + red[6] + red[7];
    const float mu  = s * (1.0f / E_DIM);
    const float var = ss * (1.0f / E_DIM) - mu * mu;
    const float rs  = rsqrtf(var + 1e-5f);
    const float4 gv = reinterpret_cast<const float4*>(g)[t];
    const float4 bv = reinterpret_cast<const float4*>(bt)[t];
    ushort4 o;
    o.x = f2b((v.x - mu) * rs * gv.x + bv.x);
    o.y = f2b((v.y - mu) * rs * gv.y + bv.y);
    o.z = f2b((v.z - mu) * rs * gv.z + bv.z);
    o.w = f2b((v.w - mu) * rs * gv.w + bv.w);
    reinterpret_cast<ushort4*>(xn + (size_t)row * E_DIM)[t] = o;
}

// ------------------------------------------------ shared 128x128xK mainloop
__device__ __forceinline__ void gemm128_mainloop(
    const unsigned short* __restrict__ A, const unsigned short* __restrict__ BT,
    int m0, int n0, unsigned short* As, unsigned short* Bs, f32x4 acc[4][4]) {
    const int t = threadIdx.x;
    const int l = t & 63;
    const int w = t >> 6;
    const int wr = w >> 1, wc = w & 1;
    const int lr = l >> 3;          // row within 8-row staging chunk
    const int gs = (l & 7) ^ lr;    // pre-swizzled source slot
    const int il = l & 15;          // fragment row
    const int kq = l >> 4;          // k quarter

    for (int kt = 0; kt < E_DIM; kt += 64) {
        __syncthreads();            // previous tile's reads done
        #pragma unroll
        for (int c = 0; c < 4; ++c) {
            const int cc = w * 4 + c;
            gload_lds16(A + (size_t)(m0 + cc * 8 + lr) * E_DIM + kt + gs * 8, As + cc * 512);
        }
        #pragma unroll
        for (int c = 0; c < 4; ++c) {
            const int cc = w * 4 + c;
            gload_lds16(BT + (size_t)(n0 + cc * 8 + lr) * E_DIM + kt + gs * 8, Bs + cc * 512);
        }
        __syncthreads();            // drains vmcnt -> tile ready
        #pragma unroll
        for (int ks = 0; ks < 2; ++ks) {
            bf16x8 af[4], bfr[4];
            #pragma unroll
            for (int mi = 0; mi < 4; ++mi) {
                const int r = wr * 64 + mi * 16 + il;
                af[mi] = *reinterpret_cast<const bf16x8*>(As + r * 64 + ((ks * 4 + kq) ^ (r & 7)) * 8);
            }
            #pragma unroll
            for (int ni = 0; ni < 4; ++ni) {
                const int r = wc * 64 + ni * 16 + il;
                bfr[ni] = *reinterpret_cast<const bf16x8*>(Bs + r * 64 + ((ks * 4 + kq) ^ (r & 7)) * 8);
            }
            #pragma unroll
            for (int mi = 0; mi < 4; ++mi)
                #pragma unroll
                for (int ni = 0; ni < 4; ++ni)
                    acc[mi][ni] = __builtin_amdgcn_mfma_f32_16x16x32_bf16(af[mi], bfr[ni], acc[mi][ni], 0, 0, 0);
        }
    }
}

// ------------------------------------------------ QKV projection
__global__ __launch_bounds__(256) void qkv_kernel(
    const unsigned short* __restrict__ xn,
    const unsigned short* __restrict__ wqT, const float* __restrict__ bq,
    const unsigned short* __restrict__ wkT, const float* __restrict__ bk,
    const unsigned short* __restrict__ wvT, const float* __restrict__ bv,
    unsigned short* __restrict__ qo, unsigned short* __restrict__ ko,
    unsigned short* __restrict__ vo) {
    __shared__ __align__(16) unsigned short As[8192];
    __shared__ __align__(16) unsigned short Bs[8192];
    const int mat = blockIdx.z;
    const unsigned short* BT = (mat == 0) ? wqT : (mat == 1) ? wkT : wvT;
    const float* bias = (mat == 0) ? bq : (mat == 1) ? bk : bv;
    const int m0 = blockIdx.x * 128, n0 = blockIdx.y * 128;

    const f32x4 ZERO = {0.f, 0.f, 0.f, 0.f};
    f32x4 acc[4][4];
    #pragma unroll
    for (int i = 0; i < 4; ++i)
        #pragma unroll
        for (int j = 0; j < 4; ++j) acc[i][j] = ZERO;

    gemm128_mainloop(xn, BT, m0, n0, As, Bs, acc);

    const int t = threadIdx.x, l = t & 63, w = t >> 6;
    const int wr = w >> 1, wc = w & 1;
    const int il = l & 15, kq = l >> 4;
    const int b = m0 >> 11;
    const float qsc = (mat == 0) ? 0.125f : 1.0f;
    unsigned short* outp = (mat == 0) ? qo : ko;

    #pragma unroll
    for (int ni = 0; ni < 4; ++ni) {
        const int n = n0 + wc * 64 + ni * 16 + il;
        const int h = n >> 6, d = n & 63;
        const float bb = bias[n];
        #pragma unroll
        for (int mi = 0; mi < 4; ++mi) {
            const int mbase = m0 + wr * 64 + mi * 16 + kq * 4;
            const int sbase = mbase & (S_LEN - 1);
            if (mat == 2) {
                ushort4 o;
                o.x = f2b(acc[mi][ni][0] + bb);
                o.y = f2b(acc[mi][ni][1] + bb);
                o.z = f2b(acc[mi][ni][2] + bb);
                o.w = f2b(acc[mi][ni][3] + bb);
                *reinterpret_cast<ushort4*>(vo + ((size_t)(b * NHEAD + h) * DHEAD + d) * S_LEN + sbase) = o;
            } else {
                #pragma unroll
                for (int r = 0; r < 4; ++r)
                    outp[((size_t)(b * NHEAD + h) * S_LEN + sbase + r) * DHEAD + d] =
                        f2b((acc[mi][ni][r] + bb) * qsc);
            }
        }
    }
}

// ------------------------------------------------ flash attention tile (128 KV)
// SWAPPED QK^T: s = mfma(K, Q) -> lane holds S[q = il][kv = nf*16 + kq*4 + r].
// Softmax is lane-local (1 q-row/lane): 31-op trees + 2 shfl_xor (16, 32).
// P pack: 4 consecutive k per nf -> one 8B write. P LDS [16 q][128 k],
// 16B-slot swizzle slot^il (involution both sides).
// O keeps the OLD layout (q = kq*4+r, d = nf*16+il); sc & 1/l hop via __shfl.
__device__ __forceinline__ void attn_tile128(
    const unsigned short* __restrict__ Kc, const unsigned short* __restrict__ Vc,
    unsigned short* __restrict__ Pw, const bf16x8* qf,
    float& m, float& lsum, f32x4* o,
    int il, int kq, int w, int qi0, int kt0, bool do_mask) {
    const f32x4 ZERO = {0.f, 0.f, 0.f, 0.f};
    f32x4 s[8];
    #pragma unroll
    for (int nf = 0; nf < 8; ++nf) s[nf] = ZERO;
    __builtin_amdgcn_s_setprio(1);
    #pragma unroll
    for (int ks = 0; ks < 2; ++ks)
        #pragma unroll
        for (int nf = 0; nf < 8; ++nf) {
            const int j = nf * 16 + il;
            const bf16x8 kf = *reinterpret_cast<const bf16x8*>(
                Kc + j * 64 + (((ks * 4 + kq) ^ (il & 7)) * 8));
            s[nf] = __builtin_amdgcn_mfma_f32_16x16x32_bf16(kf, qf[ks], s[nf], 0, 0, 0);
        }
    __builtin_amdgcn_s_setprio(0);
    if (do_mask) {
        const int i = qi0 + w * 16 + il;
        #pragma unroll
        for (int nf = 0; nf < 8; ++nf)
            #pragma unroll
            for (int r = 0; r < 4; ++r) {
                const int j = kt0 + nf * 16 + kq * 4 + r;
                if (j < i) s[nf][r] = -INFINITY;
            }
    }
    // local max over this lane's 32 values (one q-row), then 2-step cross-kq reduce
    float tnf[8];
    #pragma unroll
    for (int nf = 0; nf < 8; ++nf)
        tnf[nf] = fmaxf(fmaxf(s[nf][0], s[nf][1]), fmaxf(s[nf][2], s[nf][3]));
    float tm = fmaxf(fmaxf(fmaxf(tnf[0], tnf[1]), fmaxf(tnf[2], tnf[3])),
                     fmaxf(fmaxf(tnf[4], tnf[5]), fmaxf(tnf[6], tnf[7])));
    tm = fmaxf(tm, __shfl_xor(tm, 16));
    tm = fmaxf(tm, __shfl_xor(tm, 32));

    // defer-max (T13): only rescale when some row's max grew past THR=8
    float sc = 1.0f;
    const bool resc = __any(tm > m + 8.0f);
    if (resc) {
        const float nm = fmaxf(m, tm);
        sc = __expf(m - nm);
        m = nm;
    }

    // p = exp(s - m); pack 4 consecutive k -> 8B LDS write; local sum tree
    float ps0 = 0.f, ps1 = 0.f;
    #pragma unroll
    for (int nf = 0; nf < 8; ++nf) {
        const float e0 = __expf(s[nf][0] - m);
        const float e1 = __expf(s[nf][1] - m);
        const float e2 = __expf(s[nf][2] - m);
        const float e3 = __expf(s[nf][3] - m);
        ps0 += e0 + e1; ps1 += e2 + e3;
        ushort4 pk;
        pk.x = f2b(e0); pk.y = f2b(e1); pk.z = f2b(e2); pk.w = f2b(e3);
        *reinterpret_cast<ushort4*>(
            Pw + il * 128 + (((2 * nf + (kq >> 1)) ^ il) << 3) + ((kq & 1) << 2)) = pk;
    }
    float ps = ps0 + ps1;
    ps += __shfl_xor(ps, 16);
    ps += __shfl_xor(ps, 32);
    lsum = lsum * sc + ps;

    if (resc) {   // rescale O in its (q = kq*4+r) domain
        #pragma unroll
        for (int r = 0; r < 4; ++r) {
            const float scq = __shfl(sc, kq * 4 + r);
            #pragma unroll
            for (int nf = 0; nf < 4; ++nf) o[nf][r] *= scq;
        }
    }

    // PV: A = P (from LDS), B = V^T rows (kv-contiguous)
    __builtin_amdgcn_s_setprio(1);
    #pragma unroll
    for (int ks = 0; ks < 4; ++ks) {
        const bf16x8 pa = *reinterpret_cast<const bf16x8*>(
            Pw + il * 128 + (((ks * 4 + kq) ^ il) << 3));
        #pragma unroll
        for (int nf = 0; nf < 4; ++nf) {
            const int dl = nf * 16 + il;
            const bf16x8 vf = *reinterpret_cast<const bf16x8*>(
                Vc + dl * 128 + (((ks * 4 + kq) ^ il) << 3));
            o[nf] = __builtin_amdgcn_mfma_f32_16x16x32_bf16(pa, vf, o[nf], 0, 0, 0);
        }
    }
    __builtin_amdgcn_s_setprio(0);
}

// ------------------------------------------------ flash attention (mask: attend j >= i)
// PAIRED q-tiles for load balance: block does q-tile qtA and 31-qtA -> uniform
// 17 units of 128 KV per block. 512 blocks, 2/CU, no drain tail.
__global__ __launch_bounds__(256) void attn_kernel(
    const unsigned short* __restrict__ q,    // [bh][s][d], pre-scaled
    const unsigned short* __restrict__ k,    // [bh][s][d]
    const unsigned short* __restrict__ vt,   // [bh][d][s]
    unsigned short* __restrict__ hb) {       // [4096][1024] bf16
    __shared__ __align__(16) unsigned short Ks[2][8192];   // 128x64
    __shared__ __align__(16) unsigned short Vs[2][8192];   // 64x128
    __shared__ __align__(16) unsigned short Ps[8192];      // 4 waves x 16x128
    const int qtA = blockIdx.x;              // 0..15
    const int bh  = blockIdx.y;
    const int qiA = qtA * 64;
    const int qiB = (31 - qtA) * 64;
    const int startA = qiA & ~127;
    const int startB = qiB & ~127;
    const unsigned short* qp = q + (size_t)bh * S_LEN * DHEAD;
    const unsigned short* kp = k + (size_t)bh * S_LEN * DHEAD;
    const unsigned short* vp = vt + (size_t)bh * DHEAD * S_LEN;
    const int t = threadIdx.x, l = t & 63, w = t >> 6;
    const int il = l & 15, kq = l >> 4;
    const int lr = l >> 3, kls = l & 7;      // K staging: 8 rows x 8 slots
    const int vr = l >> 4, vs = l & 15;      // V staging: 4 rows x 16 slots

    auto stage = [&](int buf, int kt) {
        #pragma unroll
        for (int c = 0; c < 4; ++c) {
            const int cc = w * 4 + c;
            const int krow = cc * 8 + lr;
            gload_lds16(kp + (size_t)(kt + krow) * DHEAD + (kls ^ lr) * 8, &Ks[buf][cc * 512]);
            const int vrow = cc * 4 + vr;
            gload_lds16(vp + (size_t)vrow * S_LEN + kt + (vs ^ (vrow & 15)) * 8, &Vs[buf][cc * 512]);
        }
    };

    const f32x4 ZERO = {0.f, 0.f, 0.f, 0.f};
    bf16x8 qfA[2], qfB[2];
    {
        const int rA = qiA + w * 16 + il;
        const int rB = qiB + w * 16 + il;
        qfA[0] = *reinterpret_cast<const bf16x8*>(qp + (size_t)rA * DHEAD + kq * 8);
        qfA[1] = *reinterpret_cast<const bf16x8*>(qp + (size_t)rA * DHEAD + 32 + kq * 8);
        qfB[0] = *reinterpret_cast<const bf16x8*>(qp + (size_t)rB * DHEAD + kq * 8);
        qfB[1] = *reinterpret_cast<const bf16x8*>(qp + (size_t)rB * DHEAD + 32 + kq * 8);
    }

    float mA = -INFINITY, lA = 0.f, mB = -INFINITY, lB = 0.f;
    f32x4 oA[4], oB[4];
    #pragma unroll
    for (int nf = 0; nf < 4; ++nf) { oA[nf] = ZERO; oB[nf] = ZERO; }

    unsigned short* Pw = Ps + w * 2048;   // per-wave 16x128 P tile

    stage(0, startA);
    __syncthreads();
    int cur = 0;

    for (int kt0 = startA; kt0 < S_LEN; kt0 += 128) {
        if (kt0 + 128 < S_LEN) stage(cur ^ 1, kt0 + 128);
        attn_tile128(Ks[cur], Vs[cur], Pw, qfA, mA, lA, oA, il, kq, w, qiA, kt0, kt0 == startA);
        if (kt0 >= startB)
            attn_tile128(Ks[cur], Vs[cur], Pw, qfB, mB, lB, oB, il, kq, w, qiB, kt0, kt0 == startB);
        __syncthreads();   // drains vmcnt (next tile staged) + protects buf reuse
        cur ^= 1;
    }

    const int b = bh >> 4, hh = bh & 15;
    const float rvA = 1.0f / lA, rvB = 1.0f / lB;
    float rlA[4], rlB[4];
    #pragma unroll
    for (int r = 0; r < 4; ++r) {
        rlA[r] = __shfl(rvA, kq * 4 + r);
        rlB[r] = __shfl(rvB, kq * 4 + r);
    }
    #pragma unroll
    for (int nf = 0; nf < 4; ++nf) {
        const int col = hh * 64 + nf * 16 + il;
        #pragma unroll
        for (int r = 0; r < 4; ++r) {
            const int rowA = qiA + w * 16 + kq * 4 + r;
            const int rowB = qiB + w * 16 + kq * 4 + r;
            hb[(size_t)(b * S_LEN + rowA) * E_DIM + col] = f2b(oA[nf][r] * rlA[r]);
            hb[(size_t)(b * S_LEN + rowB) * E_DIM + col] = f2b(oB[nf][r] * rlB[r]);
        }
    }
}

// ------------------------------------------------ output proj + bias + residual
__global__ __launch_bounds__(256) void oproj_kernel(
    const unsigned short* __restrict__ hbuf, const unsigned short* __restrict__ w0T,
    const float* __restrict__ b0, const float* __restrict__ x,
    float* __restrict__ out) {
    __shared__ __align__(16) unsigned short As[8192];
    __shared__ __align__(16) unsigned short Bs[8192];
    const int m0 = blockIdx.x * 128, n0 = blockIdx.y * 128;

    const f32x4 ZERO = {0.f, 0.f, 0.f, 0.f};
    f32x4 acc[4][4];
    #pragma unroll
    for (int i = 0; i < 4; ++i)
        #pragma unroll
        for (int j = 0; j < 4; ++j) acc[i][j] = ZERO;

    gemm128_mainloop(hbuf, w0T, m0, n0, As, Bs, acc);

    const int t = threadIdx.x, l = t & 63, w = t >> 6;
    const int wr = w >> 1, wc = w & 1;
    const int il = l & 15, kq = l >> 4;
    #pragma unroll
    for (int ni = 0; ni < 4; ++ni) {
        const int n = n0 + wc * 64 + ni * 16 + il;
        const float bb = b0[n];
        #pragma unroll
        for (int mi = 0; mi < 4; ++mi) {
            const int mbase = m0 + wr * 64 + mi * 16 + kq * 4;
            #pragma unroll
            for (int r = 0; r < 4; ++r) {
                const size_t idx = (size_t)(mbase + r) * E_DIM + n;
                out[idx] = acc[mi][ni][r] + bb + x[idx];
            }
        }
    }
}

// ----------------------------------------------------------------- launch
extern "C" void kernel_launch(void* const* d_in, const int* in_sizes, int n_in,
                              void* d_out, int out_size, void* d_ws, size_t ws_size,
                              hipStream_t stream) {
    (void)in_sizes; (void)n_in; (void)out_size; (void)ws_size;
    const float* x    = (const float*)d_in[0];
    const float* ln_g = (const float*)d_in[1];
    const float* ln_b = (const float*)d_in[2];
    const float* wq   = (const float*)d_in[3];
    const float* bq   = (const float*)d_in[4];
    const float* wk   = (const float*)d_in[5];
    const float* bk   = (const float*)d_in[6];
    const float* wv   = (const float*)d_in[7];
    const float* bv   = (const float*)d_in[8];
    const float* w0   = (const float*)d_in[9];
    const float* b0   = (const float*)d_in[10];

    uint8_t* ws = (uint8_t*)d_ws;
    unsigned short* xnb = (unsigned short*)(ws);                 // 8 MB (reused as hb)
    unsigned short* qb  = (unsigned short*)(ws + (8u  << 20));   // 8 MB
    unsigned short* kb  = (unsigned short*)(ws + (16u << 20));   // 8 MB
    unsigned short* vtb = (unsigned short*)(ws + (24u << 20));   // 8 MB (V^T)
    unsigned short* wqT = (unsigned short*)(ws + (32u << 20));   // 2 MB
    unsigned short* wkT = (unsigned short*)(ws + (34u << 20));
    unsigned short* wvT = (unsigned short*)(ws + (36u << 20));
    unsigned short* w0T = (unsigned short*)(ws + (38u << 20));
    unsigned short* hbf = xnb;   // xn is dead after qkv_kernel; alias to cut footprint

    hipLaunchKernelGGL(wtrans_kernel, dim3(16, 16, 4), dim3(256), 0, stream,
                       wq, wk, wv, w0, wqT, wkT, wvT, w0T);
    hipLaunchKernelGGL(ln_kernel, dim3(NROWS), dim3(256), 0, stream, x, ln_g, ln_b, xnb);
    hipLaunchKernelGGL(qkv_kernel, dim3(32, 8, 3), dim3(256), 0, stream,
                       xnb, wqT, bq, wkT, bk, wvT, bv, qb, kb, vtb);
    hipLaunchKernelGGL(attn_kernel, dim3(16, 32), dim3(256), 0, stream, qb, kb, vtb, hbf);
    hipLaunchKernelGGL(oproj_kernel, dim3(32, 8), dim3(256), 0, stream,
                       hbf, w0T, b0, x, (float*)d_out);
}